// Round 1
// baseline (3479.079 us; speedup 1.0000x reference)
//
#include <hip/hip_runtime.h>

// Problem constants (from reference)
#define U_N 50000
#define I_N 100000
#define E_N 1600000
#define D_DIM 64
#define H_N 8
#define HID_N 8
#define B_N 16384
#define UI_N (U_N + I_N)   // 150000

// ---------------- CSR build ----------------

__global__ void k_hist(const int* __restrict__ eu, const int* __restrict__ ei,
                       int* __restrict__ cnt) {
  int e = blockIdx.x * blockDim.x + threadIdx.x;
  if (e < E_N) {
    atomicAdd(&cnt[eu[e]], 1);
    atomicAdd(&cnt[U_N + ei[e]], 1);
  }
}

// Each block scans 1024 elements (256 threads x 4)
__global__ void k_scan1(const int* __restrict__ cnt, int* __restrict__ ptr,
                        int* __restrict__ bsum, int n) {
  __shared__ int lds[256];
  int t = threadIdx.x;
  int base = blockIdx.x * 1024 + t * 4;
  int v0 = (base + 0 < n) ? cnt[base + 0] : 0;
  int v1 = (base + 1 < n) ? cnt[base + 1] : 0;
  int v2 = (base + 2 < n) ? cnt[base + 2] : 0;
  int v3 = (base + 3 < n) ? cnt[base + 3] : 0;
  int s = v0 + v1 + v2 + v3;
  lds[t] = s;
  __syncthreads();
  int val = s;
  for (int off = 1; off < 256; off <<= 1) {
    int x = (t >= off) ? lds[t - off] : 0;
    __syncthreads();
    val += x;
    lds[t] = val;
    __syncthreads();
  }
  int excl = val - s;
  if (base + 0 < n) ptr[base + 0] = excl;
  if (base + 1 < n) ptr[base + 1] = excl + v0;
  if (base + 2 < n) ptr[base + 2] = excl + v0 + v1;
  if (base + 3 < n) ptr[base + 3] = excl + v0 + v1 + v2;
  if (t == 255) bsum[blockIdx.x] = val;
}

__global__ void k_scan2(int* __restrict__ bsum, int nb) {
  __shared__ int lds[256];
  int t = threadIdx.x;
  int v = (t < nb) ? bsum[t] : 0;
  lds[t] = v;
  __syncthreads();
  int val = v;
  for (int off = 1; off < 256; off <<= 1) {
    int x = (t >= off) ? lds[t - off] : 0;
    __syncthreads();
    val += x;
    lds[t] = val;
    __syncthreads();
  }
  if (t < nb) bsum[t] = val - v;  // exclusive
}

__global__ void k_scan3(int* __restrict__ ptr, const int* __restrict__ bsum,
                        int n, int total) {
  int i = blockIdx.x * blockDim.x + threadIdx.x;
  if (i < n) ptr[i] += bsum[i >> 10];
  if (i == 0) ptr[n] = total;
}

__global__ void k_scatter(const int* __restrict__ eu, const int* __restrict__ ei,
                          const int* __restrict__ ptr, int* __restrict__ cur,
                          int* __restrict__ col) {
  int e = blockIdx.x * blockDim.x + threadIdx.x;
  if (e >= E_N) return;
  int u = eu[e], it = ei[e];
  int p1 = ptr[u] + atomicAdd(&cur[u], 1);
  col[p1] = it;
  int p2 = ptr[U_N + it] + atomicAdd(&cur[U_N + it], 1);
  col[p2] = u;
}

// ---------------- Matmul + score ----------------
// layer==1: W is [8][64][8] (head,in,hid); effective col c=(h*8+j); a row-stride 16, offset aoff.
//           score[node*8+h] = sum_j feat[node][h*8+j]*a[h*16+aoff+j]
// layer==2: W is [64][64] row-major (in,out); score[node] = sum_c feat[node][c]*a[c]
__global__ void k_mm(const float* __restrict__ X, const float* __restrict__ W,
                     const float* __restrict__ a, int aoff, int layer,
                     float* __restrict__ feat, float* __restrict__ score, int N) {
  __shared__ float Wl[64 * 64];
  __shared__ float Xs[16 * 64];
  int t = threadIdx.x;
  for (int k = 0; k < 16; k++) {
    int m = t + 256 * k;
    int d = m >> 6, c = m & 63;
    float w;
    if (layer == 1)
      w = W[(c >> 3) * 512 + d * 8 + (c & 7)];
    else
      w = W[m];
    Wl[m] = w;
  }
  int base = blockIdx.x * 16;
  for (int k = 0; k < 4; k++) {
    int m = t + 256 * k;
    int node = base + (m >> 6);
    Xs[m] = (node < N) ? X[node * 64 + (m & 63)] : 0.f;
  }
  __syncthreads();
  int c = t & 63, q = t >> 6;
  float acc0 = 0.f, acc1 = 0.f, acc2 = 0.f, acc3 = 0.f;
  for (int d = 0; d < 64; d++) {
    float w = Wl[d * 64 + c];
    acc0 += Xs[(q + 0) * 64 + d] * w;
    acc1 += Xs[(q + 4) * 64 + d] * w;
    acc2 += Xs[(q + 8) * 64 + d] * w;
    acc3 += Xs[(q + 12) * 64 + d] * w;
  }
  float accs[4] = {acc0, acc1, acc2, acc3};
  float av;
  if (layer == 1)
    av = a[(c >> 3) * 16 + aoff + (c & 7)];
  else
    av = a[c];
  for (int k = 0; k < 4; k++) {
    int node = base + q + 4 * k;
    if (node < N) {  // wave-uniform branch (q uniform per wave)
      feat[node * 64 + c] = accs[k];
      float s = accs[k] * av;
      if (layer == 1) {
        s += __shfl_xor(s, 1);
        s += __shfl_xor(s, 2);
        s += __shfl_xor(s, 4);
        if ((c & 7) == 0) score[node * 8 + (c >> 3)] = s;
      } else {
        for (int off = 1; off < 64; off <<= 1) s += __shfl_xor(s, off);
        if (c == 0) score[node] = s;
      }
    }
  }
}

// ---------------- Per-node edge aggregation (one wave per node) ----------------
// out[n] = elu(self_feat[n] + (deg>0 ? sum_e w_e*nbr_feat[col[e]] / sum_e w_e : 0))
// w_e = exp(-leaky(self_score + nbr_score)); sshift=3,scount=8 for layer1 (per-head), 6,1 for layer2
__global__ void k_agg(const int* __restrict__ ptr, const int* __restrict__ col,
                      const float* __restrict__ nbr_feat, const float* __restrict__ nbr_score,
                      const float* __restrict__ self_feat, const float* __restrict__ self_score,
                      float* __restrict__ out, int N, int node_off, int sshift, int scount) {
  int gid = blockIdx.x * blockDim.x + threadIdx.x;
  int n = gid >> 6;
  if (n >= N) return;
  int lane = threadIdx.x & 63;
  int sidx = lane >> sshift;
  int beg = ptr[node_off + n], end = ptr[node_off + n + 1];
  float sself = self_score[n * scount + sidx];
  float acc = 0.f, wsum = 0.f;
  for (int p = beg; p < end; p++) {
    int nb = col[p];
    float x = sself + nbr_score[nb * scount + sidx];
    float lx = (x >= 0.f) ? x : 0.2f * x;
    float w = __expf(-lx);
    wsum += w;
    acc += w * nbr_feat[nb * 64 + lane];
  }
  float v = self_feat[n * 64 + lane];
  if (end > beg) v += acc / wsum;
  out[n * 64 + lane] = (v > 0.f) ? v : (__expf(v) - 1.f);
}

// ---------------- Final pair dot ----------------
__global__ void k_dot(const int* __restrict__ uIdx, const int* __restrict__ iIdx,
                      const float* __restrict__ u_f, const float* __restrict__ i_f,
                      float* __restrict__ out) {
  int gid = blockIdx.x * blockDim.x + threadIdx.x;
  int b = gid >> 6;
  if (b >= B_N) return;
  int lane = threadIdx.x & 63;
  float v = u_f[uIdx[b] * 64 + lane] * i_f[iIdx[b] * 64 + lane];
  for (int off = 1; off < 64; off <<= 1) v += __shfl_xor(v, off);
  if (lane == 0) out[b] = v;
}

extern "C" void kernel_launch(void* const* d_in, const int* in_sizes, int n_in,
                              void* d_out, int out_size, void* d_ws, size_t ws_size,
                              hipStream_t stream) {
  const int* userIdx = (const int*)d_in[0];
  const int* itemIdx = (const int*)d_in[1];
  const int* edge_u = (const int*)d_in[2];
  const int* edge_i = (const int*)d_in[3];
  const float* uEmbd = (const float*)d_in[4];
  const float* iEmbd = (const float*)d_in[5];
  const float* Wu_h = (const float*)d_in[6];
  const float* Wi_h = (const float*)d_in[7];
  const float* a_h = (const float*)d_in[8];
  const float* Wu_out = (const float*)d_in[9];
  const float* Wi_out = (const float*)d_in[10];
  const float* a_out = (const float*)d_in[11];
  float* out = (float*)d_out;

  // workspace layout (512B aligned slices)
  char* w = (char*)d_ws;
  size_t off = 0;
  auto alloc = [&](size_t bytes) -> void* {
    void* p = w + off;
    off += (bytes + 511) & ~(size_t)511;
    return p;
  };
  int* cnt = (int*)alloc((size_t)2 * UI_N * 4);  // cnt[0..UI) then cur[0..UI)
  int* cur = cnt + UI_N;
  int* ptr = (int*)alloc((size_t)(UI_N + 1) * 4);
  int* bsum = (int*)alloc(1024);
  int* col = (int*)alloc((size_t)2 * E_N * 4);
  float* u_h1 = (float*)alloc((size_t)U_N * 64 * 4);  // reused as u_h2
  float* i_h1 = (float*)alloc((size_t)I_N * 64 * 4);  // reused as i_h2
  float* su1 = (float*)alloc((size_t)U_N * 8 * 4);
  float* si1 = (float*)alloc((size_t)I_N * 8 * 4);
  float* hu = (float*)alloc((size_t)U_N * 64 * 4);  // reused as u_f
  float* hi = (float*)alloc((size_t)I_N * 64 * 4);  // reused as i_f
  float* su2 = (float*)alloc((size_t)U_N * 4);
  float* si2 = (float*)alloc((size_t)I_N * 4);

  // 1. CSR/CSC build (shared by both layers)
  hipMemsetAsync(cnt, 0, (size_t)2 * UI_N * 4, stream);
  k_hist<<<E_N / 256, 256, 0, stream>>>(edge_u, edge_i, cnt);
  const int nb1 = (UI_N + 1023) / 1024;  // 147
  k_scan1<<<nb1, 256, 0, stream>>>(cnt, ptr, bsum, UI_N);
  k_scan2<<<1, 256, 0, stream>>>(bsum, nb1);
  k_scan3<<<(UI_N + 255) / 256, 256, 0, stream>>>(ptr, bsum, UI_N, 2 * E_N);
  k_scatter<<<E_N / 256, 256, 0, stream>>>(edge_u, edge_i, ptr, cur, col);

  // 2. Layer 1 matmuls (head-major 64-col output + per-head scores)
  k_mm<<<U_N / 16, 256, 0, stream>>>(uEmbd, Wu_h, a_h, 0, 1, u_h1, su1, U_N);
  k_mm<<<I_N / 16, 256, 0, stream>>>(iEmbd, Wi_h, a_h, 8, 1, i_h1, si1, I_N);

  // 3. Layer 1 aggregation (+ fused ELU) -> hu, hi
  k_agg<<<U_N * 64 / 256, 256, 0, stream>>>(ptr, col, i_h1, si1, u_h1, su1, hu,
                                            U_N, 0, 3, 8);
  k_agg<<<I_N * 64 / 256, 256, 0, stream>>>(ptr, col, u_h1, su1, i_h1, si1, hi,
                                            I_N, U_N, 3, 8);

  // 4. Layer 2 matmuls (overwrite layer-1 feature buffers; those are dead now)
  k_mm<<<U_N / 16, 256, 0, stream>>>(hu, Wu_out, a_out, 0, 2, u_h1, su2, U_N);
  k_mm<<<I_N / 16, 256, 0, stream>>>(hi, Wi_out, a_out + 64, 0, 2, i_h1, si2, I_N);

  // 5. Layer 2 aggregation (+ final ELU) -> u_f (over hu), i_f (over hi)
  k_agg<<<U_N * 64 / 256, 256, 0, stream>>>(ptr, col, i_h1, si2, u_h1, su2, hu,
                                            U_N, 0, 6, 1);
  k_agg<<<I_N * 64 / 256, 256, 0, stream>>>(ptr, col, u_h1, su2, i_h1, si2, hi,
                                            I_N, U_N, 6, 1);

  // 6. Final per-pair dot
  k_dot<<<B_N * 64 / 256, 256, 0, stream>>>(userIdx, itemIdx, hu, hi, out);
}

// Round 2
// 829.520 us; speedup vs baseline: 4.1941x; 4.1941x over previous
//
#include <hip/hip_runtime.h>

#define U_N 50000
#define I_N 100000
#define E_N 1600000
#define B_N 16384
#define UI_N (U_N + I_N)   // 150000
#define NB_U 782           // ceil(50000/64)
#define NB_I 1563          // ceil(100000/64)

// ---------------- CSR build ----------------

__global__ void k_hist(const int* __restrict__ eu, const int* __restrict__ ei,
                       int* __restrict__ cnt) {
  int e = blockIdx.x * blockDim.x + threadIdx.x;
  if (e < E_N) {
    atomicAdd(&cnt[eu[e]], 1);
    atomicAdd(&cnt[U_N + ei[e]], 1);
  }
}

__global__ void k_scan1(const int* __restrict__ cnt, int* __restrict__ ptr,
                        int* __restrict__ bsum, int n) {
  __shared__ int lds[256];
  int t = threadIdx.x;
  int base = blockIdx.x * 1024 + t * 4;
  int v0 = (base + 0 < n) ? cnt[base + 0] : 0;
  int v1 = (base + 1 < n) ? cnt[base + 1] : 0;
  int v2 = (base + 2 < n) ? cnt[base + 2] : 0;
  int v3 = (base + 3 < n) ? cnt[base + 3] : 0;
  int s = v0 + v1 + v2 + v3;
  lds[t] = s;
  __syncthreads();
  int val = s;
  for (int off = 1; off < 256; off <<= 1) {
    int x = (t >= off) ? lds[t - off] : 0;
    __syncthreads();
    val += x;
    lds[t] = val;
    __syncthreads();
  }
  int excl = val - s;
  if (base + 0 < n) ptr[base + 0] = excl;
  if (base + 1 < n) ptr[base + 1] = excl + v0;
  if (base + 2 < n) ptr[base + 2] = excl + v0 + v1;
  if (base + 3 < n) ptr[base + 3] = excl + v0 + v1 + v2;
  if (t == 255) bsum[blockIdx.x] = val;
}

__global__ void k_scan2(int* __restrict__ bsum, int nb) {
  __shared__ int lds[256];
  int t = threadIdx.x;
  int v = (t < nb) ? bsum[t] : 0;
  lds[t] = v;
  __syncthreads();
  int val = v;
  for (int off = 1; off < 256; off <<= 1) {
    int x = (t >= off) ? lds[t - off] : 0;
    __syncthreads();
    val += x;
    lds[t] = val;
    __syncthreads();
  }
  if (t < nb) bsum[t] = val - v;
}

__global__ void k_scan3(int* __restrict__ ptr, const int* __restrict__ bsum,
                        int n, int total) {
  int i = blockIdx.x * blockDim.x + threadIdx.x;
  if (i < n) ptr[i] += bsum[i >> 10];
  if (i == 0) ptr[n] = total;
}

__global__ void k_scatter(const int* __restrict__ eu, const int* __restrict__ ei,
                          const int* __restrict__ ptr, int* __restrict__ cur,
                          int* __restrict__ col) {
  int e = blockIdx.x * blockDim.x + threadIdx.x;
  if (e >= E_N) return;
  int u = eu[e], it = ei[e];
  int p1 = ptr[u] + atomicAdd(&cur[u], 1);
  col[p1] = it;
  int p2 = ptr[U_N + it] + atomicAdd(&cur[U_N + it], 1);
  col[p2] = u;
}

// ---------------- Fused matmul + attention scores (users + items, one launch) ----------------
// 64 nodes/block, 256 threads, 8x2 register tile. layer1: W [8][64][8] head-major
// repacked to Wl[d*64 + h*8 + j]; layer2: W [64][64] row-major direct.
__global__ __launch_bounds__(256) void k_mm2(
    const float* __restrict__ Xu, const float* __restrict__ Xi,
    const float* __restrict__ Wu, const float* __restrict__ Wi,
    const float* __restrict__ a, int layer,
    float* __restrict__ featU, float* __restrict__ featI,
    float* __restrict__ scoreU, float* __restrict__ scoreI) {
  __shared__ float Wl[4096];
  __shared__ float Xs[4096];
  const bool isU = blockIdx.x < NB_U;
  const int N = isU ? U_N : I_N;
  const int base = (isU ? blockIdx.x : blockIdx.x - NB_U) * 64;
  const float* X = isU ? Xu : Xi;
  const float* W = isU ? Wu : Wi;
  float* feat = isU ? featU : featI;
  float* score = isU ? scoreU : scoreI;
  const int aoff = (layer == 1) ? (isU ? 0 : 8) : (isU ? 0 : 64);
  int t = threadIdx.x;

  if (layer == 1) {
#pragma unroll
    for (int k = 0; k < 4; k++) {
      int i = t + 256 * k;            // 0..1023
      int h = i >> 7, d = (i >> 1) & 63, half = i & 1;
      float4 v = *(const float4*)(W + h * 512 + d * 8 + half * 4);
      *(float4*)(Wl + d * 64 + h * 8 + half * 4) = v;
    }
  } else {
#pragma unroll
    for (int k = 0; k < 4; k++) {
      int i = t + 256 * k;
      *(float4*)(Wl + i * 4) = *(const float4*)(W + i * 4);
    }
  }
#pragma unroll
  for (int k = 0; k < 4; k++) {
    int i = t + 256 * k;
    int r = i >> 4, ch = i & 15;
    int node = base + r;
    float4 v = make_float4(0.f, 0.f, 0.f, 0.f);
    if (node < N) v = *(const float4*)(X + (size_t)node * 64 + ch * 4);
    *(float4*)(Xs + r * 64 + ch * 4) = v;
  }
  __syncthreads();

  const int c0 = t & 31;   // cols 2c0, 2c0+1
  const int rb = t >> 5;   // rows rb + 8k
  float acc0[8], acc1[8];
#pragma unroll
  for (int k = 0; k < 8; k++) { acc0[k] = 0.f; acc1[k] = 0.f; }

  for (int d0 = 0; d0 < 64; d0 += 4) {
    float2 wA = *(float2*)(Wl + (d0 + 0) * 64 + 2 * c0);
    float2 wB = *(float2*)(Wl + (d0 + 1) * 64 + 2 * c0);
    float2 wC = *(float2*)(Wl + (d0 + 2) * 64 + 2 * c0);
    float2 wD = *(float2*)(Wl + (d0 + 3) * 64 + 2 * c0);
#pragma unroll
    for (int k = 0; k < 8; k++) {
      float4 x = *(float4*)(Xs + (rb + 8 * k) * 64 + d0);
      acc0[k] += x.x * wA.x + x.y * wB.x + x.z * wC.x + x.w * wD.x;
      acc1[k] += x.x * wA.y + x.y * wB.y + x.z * wC.y + x.w * wD.y;
    }
  }

  float av0, av1;
  if (layer == 1) {
    int h = c0 >> 2, j = 2 * (c0 & 3);
    av0 = a[h * 16 + aoff + j];
    av1 = a[h * 16 + aoff + j + 1];
  } else {
    av0 = a[aoff + 2 * c0];
    av1 = a[aoff + 2 * c0 + 1];
  }
#pragma unroll
  for (int k = 0; k < 8; k++) {
    int node = base + rb + 8 * k;
    float s = acc0[k] * av0 + acc1[k] * av1;
    s += __shfl_xor(s, 1);
    s += __shfl_xor(s, 2);
    if (layer != 1) {
      s += __shfl_xor(s, 4);
      s += __shfl_xor(s, 8);
      s += __shfl_xor(s, 16);
    }
    if (node < N) {
      float2 f;
      f.x = acc0[k];
      f.y = acc1[k];
      *(float2*)(feat + (size_t)node * 64 + 2 * c0) = f;
      if (layer == 1) {
        if ((c0 & 3) == 0) score[node * 8 + (c0 >> 2)] = s;
      } else {
        if (c0 == 0) score[node] = s;
      }
    }
  }
}

// ---------------- Fused aggregation (users + items, one launch) ----------------
// One wave per node; quarter-wave per edge (4 edges in flight); float4 gathers.
__global__ void k_agg2(const int* __restrict__ ptr, const int* __restrict__ col,
                       const float* __restrict__ fu, const float* __restrict__ fi,
                       const float* __restrict__ su, const float* __restrict__ si,
                       float* __restrict__ outU, float* __restrict__ outI, int layer) {
  int gid = blockIdx.x * blockDim.x + threadIdx.x;
  int n = gid >> 6;
  if (n >= UI_N) return;
  int l = threadIdx.x & 63;
  int g = l >> 4;       // edge group 0..3
  int cc = l & 15;      // float4 feature chunk
  bool isU = n < U_N;
  int nl = isU ? n : n - U_N;
  const float* nbrF = isU ? fi : fu;
  const float* nbrS = isU ? si : su;
  const float* selfF = isU ? fu : fi;
  const float* selfS = isU ? su : si;
  float* outp = isU ? outU : outI;

  int sc, h;
  float sself;
  if (layer == 1) {
    h = cc >> 1;
    sc = 8;
    sself = selfS[(size_t)nl * 8 + h];
  } else {
    h = 0;
    sc = 1;
    sself = selfS[nl];
  }
  int beg = ptr[n], end = ptr[n + 1];
  float4 acc = make_float4(0.f, 0.f, 0.f, 0.f);
  float wsum = 0.f;
  for (int p = beg; p < end; p += 4) {
    int idx = p + g;
    bool valid = idx < end;
    int nb = col[valid ? idx : beg];
    float x = sself + nbrS[(size_t)nb * sc + h];
    float lx = (x >= 0.f) ? x : 0.2f * x;
    float w = valid ? __expf(-lx) : 0.f;
    wsum += w;
    float4 f = *(const float4*)(nbrF + (size_t)nb * 64 + cc * 4);
    acc.x += w * f.x;
    acc.y += w * f.y;
    acc.z += w * f.z;
    acc.w += w * f.w;
  }
  acc.x += __shfl_xor(acc.x, 16); acc.x += __shfl_xor(acc.x, 32);
  acc.y += __shfl_xor(acc.y, 16); acc.y += __shfl_xor(acc.y, 32);
  acc.z += __shfl_xor(acc.z, 16); acc.z += __shfl_xor(acc.z, 32);
  acc.w += __shfl_xor(acc.w, 16); acc.w += __shfl_xor(acc.w, 32);
  wsum  += __shfl_xor(wsum, 16);  wsum  += __shfl_xor(wsum, 32);

  if (l < 16) {
    float4 v = *(const float4*)(selfF + (size_t)nl * 64 + cc * 4);
    if (end > beg) {
      float inv = 1.f / wsum;
      v.x += acc.x * inv;
      v.y += acc.y * inv;
      v.z += acc.z * inv;
      v.w += acc.w * inv;
    }
    v.x = (v.x > 0.f) ? v.x : (__expf(v.x) - 1.f);
    v.y = (v.y > 0.f) ? v.y : (__expf(v.y) - 1.f);
    v.z = (v.z > 0.f) ? v.z : (__expf(v.z) - 1.f);
    v.w = (v.w > 0.f) ? v.w : (__expf(v.w) - 1.f);
    *(float4*)(outp + (size_t)nl * 64 + cc * 4) = v;
  }
}

// ---------------- Final pair dot (16 pairs/block, quarter-wave each) ----------------
__global__ void k_dot(const int* __restrict__ uIdx, const int* __restrict__ iIdx,
                      const float* __restrict__ u_f, const float* __restrict__ i_f,
                      float* __restrict__ out) {
  int t = threadIdx.x;
  int pair = blockIdx.x * 16 + (t >> 4);
  int cc = t & 15;
  float4 a = *(const float4*)(u_f + (size_t)uIdx[pair] * 64 + cc * 4);
  float4 b = *(const float4*)(i_f + (size_t)iIdx[pair] * 64 + cc * 4);
  float v = a.x * b.x + a.y * b.y + a.z * b.z + a.w * b.w;
  v += __shfl_xor(v, 1);
  v += __shfl_xor(v, 2);
  v += __shfl_xor(v, 4);
  v += __shfl_xor(v, 8);
  if (cc == 0) out[pair] = v;
}

extern "C" void kernel_launch(void* const* d_in, const int* in_sizes, int n_in,
                              void* d_out, int out_size, void* d_ws, size_t ws_size,
                              hipStream_t stream) {
  const int* userIdx = (const int*)d_in[0];
  const int* itemIdx = (const int*)d_in[1];
  const int* edge_u = (const int*)d_in[2];
  const int* edge_i = (const int*)d_in[3];
  const float* uEmbd = (const float*)d_in[4];
  const float* iEmbd = (const float*)d_in[5];
  const float* Wu_h = (const float*)d_in[6];
  const float* Wi_h = (const float*)d_in[7];
  const float* a_h = (const float*)d_in[8];
  const float* Wu_out = (const float*)d_in[9];
  const float* Wi_out = (const float*)d_in[10];
  const float* a_out = (const float*)d_in[11];
  float* out = (float*)d_out;

  char* w = (char*)d_ws;
  size_t off = 0;
  auto alloc = [&](size_t bytes) -> void* {
    void* p = w + off;
    off += (bytes + 511) & ~(size_t)511;
    return p;
  };
  int* cnt = (int*)alloc((size_t)2 * UI_N * 4);
  int* cur = cnt + UI_N;
  int* ptr = (int*)alloc((size_t)(UI_N + 1) * 4);
  int* bsum = (int*)alloc(1024);
  int* col = (int*)alloc((size_t)2 * E_N * 4);
  float* u_h1 = (float*)alloc((size_t)U_N * 64 * 4);  // layer1 u feats; reused layer2
  float* i_h1 = (float*)alloc((size_t)I_N * 64 * 4);  // layer1 i feats; reused layer2
  float* su1 = (float*)alloc((size_t)U_N * 8 * 4);
  float* si1 = (float*)alloc((size_t)I_N * 8 * 4);
  float* hu = (float*)alloc((size_t)U_N * 64 * 4);    // layer1 out; reused as u_f
  float* hi = (float*)alloc((size_t)I_N * 64 * 4);    // layer1 out; reused as i_f
  float* su2 = (float*)alloc((size_t)U_N * 4);
  float* si2 = (float*)alloc((size_t)I_N * 4);

  // CSR/CSC build (shared by both layers)
  hipMemsetAsync(cnt, 0, (size_t)2 * UI_N * 4, stream);
  k_hist<<<E_N / 256, 256, 0, stream>>>(edge_u, edge_i, cnt);
  const int nb1 = (UI_N + 1023) / 1024;  // 147
  k_scan1<<<nb1, 256, 0, stream>>>(cnt, ptr, bsum, UI_N);
  k_scan2<<<1, 256, 0, stream>>>(bsum, nb1);
  k_scan3<<<(UI_N + 255) / 256, 256, 0, stream>>>(ptr, bsum, UI_N, 2 * E_N);
  k_scatter<<<E_N / 256, 256, 0, stream>>>(edge_u, edge_i, ptr, cur, col);

  // Layer 1: mm (+scores), then aggregation (+ELU)
  k_mm2<<<NB_U + NB_I, 256, 0, stream>>>(uEmbd, iEmbd, Wu_h, Wi_h, a_h, 1,
                                         u_h1, i_h1, su1, si1);
  k_agg2<<<UI_N * 64 / 256, 256, 0, stream>>>(ptr, col, u_h1, i_h1, su1, si1,
                                              hu, hi, 1);

  // Layer 2: mm (+scores), then aggregation (+final ELU)
  k_mm2<<<NB_U + NB_I, 256, 0, stream>>>(hu, hi, Wu_out, Wi_out, a_out, 2,
                                         u_h1, i_h1, su2, si2);
  k_agg2<<<UI_N * 64 / 256, 256, 0, stream>>>(ptr, col, u_h1, i_h1, su2, si2,
                                              hu, hi, 2);

  // Final per-pair dot
  k_dot<<<B_N / 16, 256, 0, stream>>>(userIdx, itemIdx, hu, hi, out);
}

// Round 3
// 698.438 us; speedup vs baseline: 4.9812x; 1.1877x over previous
//
#include <hip/hip_runtime.h>

#define U_N 50000
#define I_N 100000
#define E_N 1600000
#define B_N 16384
#define UI_N (U_N + I_N)   // 150000
#define NB_U 782           // ceil(50000/64)
#define NB_I 1563          // ceil(100000/64)
#define NBK 586            // ceil(150000/256) buckets, 256 nodes each
#define CAP 10240          // entries per bucket (mean 8192 max, ~22 sigma margin)
#define CHUNK 6250         // edges per block in k_build1 (256 blocks * 6250 = E)

// ---------------- CSR build: phase 1 (block-local binning into buckets) ----------------
// Each block: LDS histogram over 586 buckets for its 6250-edge chunk (both directions),
// fold in per-node degree counts (replaces old k_hist), reserve contiguous
// per-(block,bucket) ranges, re-read chunk (L2-hit) and write {key,nbr} entries.
__global__ __launch_bounds__(256) void k_build1(
    const int* __restrict__ eu, const int* __restrict__ ei,
    int* __restrict__ cnt, int* __restrict__ bcnt, int2* __restrict__ storage) {
  __shared__ int hist[NBK];
  __shared__ int lbase[NBK];
  __shared__ int loff[NBK];
  int t = threadIdx.x;
  for (int b = t; b < NBK; b += 256) { hist[b] = 0; loff[b] = 0; }
  __syncthreads();
  int e0 = blockIdx.x * CHUNK;
  int e1 = e0 + CHUNK;
  for (int e = e0 + t; e < e1; e += 256) {
    int u = eu[e], it = ei[e];
    int k2 = U_N + it;
    atomicAdd(&hist[u >> 8], 1);
    atomicAdd(&hist[k2 >> 8], 1);
    atomicAdd(&cnt[u], 1);
    atomicAdd(&cnt[k2], 1);
  }
  __syncthreads();
  for (int b = t; b < NBK; b += 256) {
    int h = hist[b];
    lbase[b] = h ? atomicAdd(&bcnt[b], h) : 0;
  }
  __syncthreads();
  for (int e = e0 + t; e < e1; e += 256) {
    int u = eu[e], it = ei[e];
    int k2 = U_N + it;
    int b1 = u >> 8;
    int s1 = lbase[b1] + atomicAdd(&loff[b1], 1);
    storage[(size_t)b1 * CAP + s1] = make_int2(u, it);
    int b2 = k2 >> 8;
    int s2 = lbase[b2] + atomicAdd(&loff[b2], 1);
    storage[(size_t)b2 * CAP + s2] = make_int2(k2, u);
  }
}

// ---------------- CSR build: phase 2 (one block per bucket -> L2-local scatter) -------
__global__ void k_build2(const int* __restrict__ bcnt, const int2* __restrict__ storage,
                         const int* __restrict__ ptr, int* __restrict__ cur,
                         int* __restrict__ col) {
  int b = blockIdx.x;
  int n = bcnt[b];
  const int2* s = storage + (size_t)b * CAP;
  for (int i = threadIdx.x; i < n; i += 256) {
    int2 e = s[i];
    int slot = ptr[e.x] + atomicAdd(&cur[e.x], 1);
    col[slot] = e.y;
  }
}

// ---------------- Prefix scans over per-node counts -> ptr ----------------
__global__ void k_scan1(const int* __restrict__ cnt, int* __restrict__ ptr,
                        int* __restrict__ bsum, int n) {
  __shared__ int lds[256];
  int t = threadIdx.x;
  int base = blockIdx.x * 1024 + t * 4;
  int v0 = (base + 0 < n) ? cnt[base + 0] : 0;
  int v1 = (base + 1 < n) ? cnt[base + 1] : 0;
  int v2 = (base + 2 < n) ? cnt[base + 2] : 0;
  int v3 = (base + 3 < n) ? cnt[base + 3] : 0;
  int s = v0 + v1 + v2 + v3;
  lds[t] = s;
  __syncthreads();
  int val = s;
  for (int off = 1; off < 256; off <<= 1) {
    int x = (t >= off) ? lds[t - off] : 0;
    __syncthreads();
    val += x;
    lds[t] = val;
    __syncthreads();
  }
  int excl = val - s;
  if (base + 0 < n) ptr[base + 0] = excl;
  if (base + 1 < n) ptr[base + 1] = excl + v0;
  if (base + 2 < n) ptr[base + 2] = excl + v0 + v1;
  if (base + 3 < n) ptr[base + 3] = excl + v0 + v1 + v2;
  if (t == 255) bsum[blockIdx.x] = val;
}

__global__ void k_scan2(int* __restrict__ bsum, int nb) {
  __shared__ int lds[256];
  int t = threadIdx.x;
  int v = (t < nb) ? bsum[t] : 0;
  lds[t] = v;
  __syncthreads();
  int val = v;
  for (int off = 1; off < 256; off <<= 1) {
    int x = (t >= off) ? lds[t - off] : 0;
    __syncthreads();
    val += x;
    lds[t] = val;
    __syncthreads();
  }
  if (t < nb) bsum[t] = val - v;
}

__global__ void k_scan3(int* __restrict__ ptr, const int* __restrict__ bsum,
                        int n, int total) {
  int i = blockIdx.x * blockDim.x + threadIdx.x;
  if (i < n) ptr[i] += bsum[i >> 10];
  if (i == 0) ptr[n] = total;
}

// ---------------- Fused matmul + attention scores (users + items, one launch) ---------
__global__ __launch_bounds__(256) void k_mm2(
    const float* __restrict__ Xu, const float* __restrict__ Xi,
    const float* __restrict__ Wu, const float* __restrict__ Wi,
    const float* __restrict__ a, int layer,
    float* __restrict__ featU, float* __restrict__ featI,
    float* __restrict__ scoreU, float* __restrict__ scoreI) {
  __shared__ float Wl[4096];
  __shared__ float Xs[4096];
  const bool isU = blockIdx.x < NB_U;
  const int N = isU ? U_N : I_N;
  const int base = (isU ? blockIdx.x : blockIdx.x - NB_U) * 64;
  const float* X = isU ? Xu : Xi;
  const float* W = isU ? Wu : Wi;
  float* feat = isU ? featU : featI;
  float* score = isU ? scoreU : scoreI;
  const int aoff = (layer == 1) ? (isU ? 0 : 8) : (isU ? 0 : 64);
  int t = threadIdx.x;

  if (layer == 1) {
#pragma unroll
    for (int k = 0; k < 4; k++) {
      int i = t + 256 * k;
      int h = i >> 7, d = (i >> 1) & 63, half = i & 1;
      float4 v = *(const float4*)(W + h * 512 + d * 8 + half * 4);
      *(float4*)(Wl + d * 64 + h * 8 + half * 4) = v;
    }
  } else {
#pragma unroll
    for (int k = 0; k < 4; k++) {
      int i = t + 256 * k;
      *(float4*)(Wl + i * 4) = *(const float4*)(W + i * 4);
    }
  }
#pragma unroll
  for (int k = 0; k < 4; k++) {
    int i = t + 256 * k;
    int r = i >> 4, ch = i & 15;
    int node = base + r;
    float4 v = make_float4(0.f, 0.f, 0.f, 0.f);
    if (node < N) v = *(const float4*)(X + (size_t)node * 64 + ch * 4);
    *(float4*)(Xs + r * 64 + ch * 4) = v;
  }
  __syncthreads();

  const int c0 = t & 31;
  const int rb = t >> 5;
  float acc0[8], acc1[8];
#pragma unroll
  for (int k = 0; k < 8; k++) { acc0[k] = 0.f; acc1[k] = 0.f; }

  for (int d0 = 0; d0 < 64; d0 += 4) {
    float2 wA = *(float2*)(Wl + (d0 + 0) * 64 + 2 * c0);
    float2 wB = *(float2*)(Wl + (d0 + 1) * 64 + 2 * c0);
    float2 wC = *(float2*)(Wl + (d0 + 2) * 64 + 2 * c0);
    float2 wD = *(float2*)(Wl + (d0 + 3) * 64 + 2 * c0);
#pragma unroll
    for (int k = 0; k < 8; k++) {
      float4 x = *(float4*)(Xs + (rb + 8 * k) * 64 + d0);
      acc0[k] += x.x * wA.x + x.y * wB.x + x.z * wC.x + x.w * wD.x;
      acc1[k] += x.x * wA.y + x.y * wB.y + x.z * wC.y + x.w * wD.y;
    }
  }

  float av0, av1;
  if (layer == 1) {
    int h = c0 >> 2, j = 2 * (c0 & 3);
    av0 = a[h * 16 + aoff + j];
    av1 = a[h * 16 + aoff + j + 1];
  } else {
    av0 = a[aoff + 2 * c0];
    av1 = a[aoff + 2 * c0 + 1];
  }
#pragma unroll
  for (int k = 0; k < 8; k++) {
    int node = base + rb + 8 * k;
    float s = acc0[k] * av0 + acc1[k] * av1;
    s += __shfl_xor(s, 1);
    s += __shfl_xor(s, 2);
    if (layer != 1) {
      s += __shfl_xor(s, 4);
      s += __shfl_xor(s, 8);
      s += __shfl_xor(s, 16);
    }
    if (node < N) {
      float2 f;
      f.x = acc0[k];
      f.y = acc1[k];
      *(float2*)(feat + (size_t)node * 64 + 2 * c0) = f;
      if (layer == 1) {
        if ((c0 & 3) == 0) score[node * 8 + (c0 >> 2)] = s;
      } else {
        if (c0 == 0) score[node] = s;
      }
    }
  }
}

// ---------------- Fused aggregation (users + items, one launch) ----------------
__global__ void k_agg2(const int* __restrict__ ptr, const int* __restrict__ col,
                       const float* __restrict__ fu, const float* __restrict__ fi,
                       const float* __restrict__ su, const float* __restrict__ si,
                       float* __restrict__ outU, float* __restrict__ outI, int layer) {
  int gid = blockIdx.x * blockDim.x + threadIdx.x;
  int n = gid >> 6;
  if (n >= UI_N) return;
  int l = threadIdx.x & 63;
  int g = l >> 4;
  int cc = l & 15;
  bool isU = n < U_N;
  int nl = isU ? n : n - U_N;
  const float* nbrF = isU ? fi : fu;
  const float* nbrS = isU ? si : su;
  const float* selfF = isU ? fu : fi;
  const float* selfS = isU ? su : si;
  float* outp = isU ? outU : outI;

  int sc, h;
  float sself;
  if (layer == 1) {
    h = cc >> 1;
    sc = 8;
    sself = selfS[(size_t)nl * 8 + h];
  } else {
    h = 0;
    sc = 1;
    sself = selfS[nl];
  }
  int beg = ptr[n], end = ptr[n + 1];
  float4 acc = make_float4(0.f, 0.f, 0.f, 0.f);
  float wsum = 0.f;
  for (int p = beg; p < end; p += 4) {
    int idx = p + g;
    bool valid = idx < end;
    int nb = col[valid ? idx : beg];
    float x = sself + nbrS[(size_t)nb * sc + h];
    float lx = (x >= 0.f) ? x : 0.2f * x;
    float w = valid ? __expf(-lx) : 0.f;
    wsum += w;
    float4 f = *(const float4*)(nbrF + (size_t)nb * 64 + cc * 4);
    acc.x += w * f.x;
    acc.y += w * f.y;
    acc.z += w * f.z;
    acc.w += w * f.w;
  }
  acc.x += __shfl_xor(acc.x, 16); acc.x += __shfl_xor(acc.x, 32);
  acc.y += __shfl_xor(acc.y, 16); acc.y += __shfl_xor(acc.y, 32);
  acc.z += __shfl_xor(acc.z, 16); acc.z += __shfl_xor(acc.z, 32);
  acc.w += __shfl_xor(acc.w, 16); acc.w += __shfl_xor(acc.w, 32);
  wsum  += __shfl_xor(wsum, 16);  wsum  += __shfl_xor(wsum, 32);

  if (l < 16) {
    float4 v = *(const float4*)(selfF + (size_t)nl * 64 + cc * 4);
    if (end > beg) {
      float inv = 1.f / wsum;
      v.x += acc.x * inv;
      v.y += acc.y * inv;
      v.z += acc.z * inv;
      v.w += acc.w * inv;
    }
    v.x = (v.x > 0.f) ? v.x : (__expf(v.x) - 1.f);
    v.y = (v.y > 0.f) ? v.y : (__expf(v.y) - 1.f);
    v.z = (v.z > 0.f) ? v.z : (__expf(v.z) - 1.f);
    v.w = (v.w > 0.f) ? v.w : (__expf(v.w) - 1.f);
    *(float4*)(outp + (size_t)nl * 64 + cc * 4) = v;
  }
}

// ---------------- Final pair dot ----------------
__global__ void k_dot(const int* __restrict__ uIdx, const int* __restrict__ iIdx,
                      const float* __restrict__ u_f, const float* __restrict__ i_f,
                      float* __restrict__ out) {
  int t = threadIdx.x;
  int pair = blockIdx.x * 16 + (t >> 4);
  int cc = t & 15;
  float4 a = *(const float4*)(u_f + (size_t)uIdx[pair] * 64 + cc * 4);
  float4 b = *(const float4*)(i_f + (size_t)iIdx[pair] * 64 + cc * 4);
  float v = a.x * b.x + a.y * b.y + a.z * b.z + a.w * b.w;
  v += __shfl_xor(v, 1);
  v += __shfl_xor(v, 2);
  v += __shfl_xor(v, 4);
  v += __shfl_xor(v, 8);
  if (cc == 0) out[pair] = v;
}

extern "C" void kernel_launch(void* const* d_in, const int* in_sizes, int n_in,
                              void* d_out, int out_size, void* d_ws, size_t ws_size,
                              hipStream_t stream) {
  const int* userIdx = (const int*)d_in[0];
  const int* itemIdx = (const int*)d_in[1];
  const int* edge_u = (const int*)d_in[2];
  const int* edge_i = (const int*)d_in[3];
  const float* uEmbd = (const float*)d_in[4];
  const float* iEmbd = (const float*)d_in[5];
  const float* Wu_h = (const float*)d_in[6];
  const float* Wi_h = (const float*)d_in[7];
  const float* a_h = (const float*)d_in[8];
  const float* Wu_out = (const float*)d_in[9];
  const float* Wi_out = (const float*)d_in[10];
  const float* a_out = (const float*)d_in[11];
  float* out = (float*)d_out;

  char* w = (char*)d_ws;
  size_t off = 0;
  auto alloc = [&](size_t bytes) -> void* {
    void* p = w + off;
    off += (bytes + 511) & ~(size_t)511;
    return p;
  };
  // counters block: cnt[UI_N] | cur[UI_N] | bcnt[NBK] — one contiguous memset
  int* cnt = (int*)alloc((size_t)(2 * UI_N + 1024) * 4);
  int* cur = cnt + UI_N;
  int* bcnt = cnt + 2 * UI_N;
  int* ptr = (int*)alloc((size_t)(UI_N + 1) * 4);
  int* bsum = (int*)alloc(1024);
  int* col = (int*)alloc((size_t)2 * E_N * 4);
  // union region: bucket storage (48 MB, dead after k_build2) aliases feature buffers
  size_t union_off = off;
  int2* storage = (int2*)alloc((size_t)NBK * CAP * 8);
  off = union_off;
  float* u_h1 = (float*)alloc((size_t)U_N * 64 * 4);
  float* i_h1 = (float*)alloc((size_t)I_N * 64 * 4);
  float* su1 = (float*)alloc((size_t)U_N * 8 * 4);
  float* si1 = (float*)alloc((size_t)I_N * 8 * 4);
  float* hu = (float*)alloc((size_t)U_N * 64 * 4);
  float* hi = (float*)alloc((size_t)I_N * 64 * 4);
  float* su2 = (float*)alloc((size_t)U_N * 4);
  float* si2 = (float*)alloc((size_t)I_N * 4);

  // CSR/CSC build (shared by both layers)
  hipMemsetAsync(cnt, 0, (size_t)(2 * UI_N + 1024) * 4, stream);
  k_build1<<<256, 256, 0, stream>>>(edge_u, edge_i, cnt, bcnt, storage);
  const int nb1 = (UI_N + 1023) / 1024;  // 147
  k_scan1<<<nb1, 256, 0, stream>>>(cnt, ptr, bsum, UI_N);
  k_scan2<<<1, 256, 0, stream>>>(bsum, nb1);
  k_scan3<<<(UI_N + 255) / 256, 256, 0, stream>>>(ptr, bsum, UI_N, 2 * E_N);
  k_build2<<<NBK, 256, 0, stream>>>(bcnt, storage, ptr, cur, col);

  // Layer 1
  k_mm2<<<NB_U + NB_I, 256, 0, stream>>>(uEmbd, iEmbd, Wu_h, Wi_h, a_h, 1,
                                         u_h1, i_h1, su1, si1);
  k_agg2<<<UI_N * 64 / 256, 256, 0, stream>>>(ptr, col, u_h1, i_h1, su1, si1,
                                              hu, hi, 1);

  // Layer 2
  k_mm2<<<NB_U + NB_I, 256, 0, stream>>>(hu, hi, Wu_out, Wi_out, a_out, 2,
                                         u_h1, i_h1, su2, si2);
  k_agg2<<<UI_N * 64 / 256, 256, 0, stream>>>(ptr, col, u_h1, i_h1, su2, si2,
                                              hu, hi, 2);

  // Final per-pair dot
  k_dot<<<B_N / 16, 256, 0, stream>>>(userIdx, itemIdx, hu, hi, out);
}

// Round 4
// 566.058 us; speedup vs baseline: 6.1462x; 1.2339x over previous
//
#include <hip/hip_runtime.h>
#include <hip/hip_fp16.h>

#define U_N 50000
#define I_N 100000
#define E_N 1600000
#define B_N 16384
#define UI_N (U_N + I_N)   // 150000
#define NB_U 782           // ceil(50000/64)
#define NB_I 1563          // ceil(100000/64)
#define NBK 586            // ceil(150000/256) buckets, 256 nodes each
#define CAP 10240          // entries per bucket (mean 8192 max, ~22 sigma margin)
#define CHUNK 6250         // edges per block in k_build1 (256 blocks * 6250 = E)

// ---------------- CSR build: phase 1 (block-local binning into buckets) ----------------
__global__ __launch_bounds__(256) void k_build1(
    const int* __restrict__ eu, const int* __restrict__ ei,
    int* __restrict__ cnt, int* __restrict__ bcnt, int2* __restrict__ storage) {
  __shared__ int hist[NBK];
  __shared__ int lbase[NBK];
  __shared__ int loff[NBK];
  int t = threadIdx.x;
  for (int b = t; b < NBK; b += 256) { hist[b] = 0; loff[b] = 0; }
  __syncthreads();
  int e0 = blockIdx.x * CHUNK;
  int e1 = e0 + CHUNK;
  for (int e = e0 + t; e < e1; e += 256) {
    int u = eu[e], it = ei[e];
    int k2 = U_N + it;
    atomicAdd(&hist[u >> 8], 1);
    atomicAdd(&hist[k2 >> 8], 1);
    atomicAdd(&cnt[u], 1);
    atomicAdd(&cnt[k2], 1);
  }
  __syncthreads();
  for (int b = t; b < NBK; b += 256) {
    int h = hist[b];
    lbase[b] = h ? atomicAdd(&bcnt[b], h) : 0;
  }
  __syncthreads();
  for (int e = e0 + t; e < e1; e += 256) {
    int u = eu[e], it = ei[e];
    int k2 = U_N + it;
    int b1 = u >> 8;
    int s1 = lbase[b1] + atomicAdd(&loff[b1], 1);
    storage[(size_t)b1 * CAP + s1] = make_int2(u, it);
    int b2 = k2 >> 8;
    int s2 = lbase[b2] + atomicAdd(&loff[b2], 1);
    storage[(size_t)b2 * CAP + s2] = make_int2(k2, u);
  }
}

// ---------------- CSR build: phase 2 (one block per bucket -> L2-local scatter) -------
__global__ void k_build2(const int* __restrict__ bcnt, const int2* __restrict__ storage,
                         const int* __restrict__ ptr, int* __restrict__ cur,
                         int* __restrict__ col) {
  int b = blockIdx.x;
  int n = bcnt[b];
  const int2* s = storage + (size_t)b * CAP;
  for (int i = threadIdx.x; i < n; i += 256) {
    int2 e = s[i];
    int slot = ptr[e.x] + atomicAdd(&cur[e.x], 1);
    col[slot] = e.y;
  }
}

// ---------------- Prefix scans over per-node counts -> ptr ----------------
__global__ void k_scan1(const int* __restrict__ cnt, int* __restrict__ ptr,
                        int* __restrict__ bsum, int n) {
  __shared__ int lds[256];
  int t = threadIdx.x;
  int base = blockIdx.x * 1024 + t * 4;
  int v0 = (base + 0 < n) ? cnt[base + 0] : 0;
  int v1 = (base + 1 < n) ? cnt[base + 1] : 0;
  int v2 = (base + 2 < n) ? cnt[base + 2] : 0;
  int v3 = (base + 3 < n) ? cnt[base + 3] : 0;
  int s = v0 + v1 + v2 + v3;
  lds[t] = s;
  __syncthreads();
  int val = s;
  for (int off = 1; off < 256; off <<= 1) {
    int x = (t >= off) ? lds[t - off] : 0;
    __syncthreads();
    val += x;
    lds[t] = val;
    __syncthreads();
  }
  int excl = val - s;
  if (base + 0 < n) ptr[base + 0] = excl;
  if (base + 1 < n) ptr[base + 1] = excl + v0;
  if (base + 2 < n) ptr[base + 2] = excl + v0 + v1;
  if (base + 3 < n) ptr[base + 3] = excl + v0 + v1 + v2;
  if (t == 255) bsum[blockIdx.x] = val;
}

__global__ void k_scan2(int* __restrict__ bsum, int nb) {
  __shared__ int lds[256];
  int t = threadIdx.x;
  int v = (t < nb) ? bsum[t] : 0;
  lds[t] = v;
  __syncthreads();
  int val = v;
  for (int off = 1; off < 256; off <<= 1) {
    int x = (t >= off) ? lds[t - off] : 0;
    __syncthreads();
    val += x;
    lds[t] = val;
    __syncthreads();
  }
  if (t < nb) bsum[t] = val - v;
}

__global__ void k_scan3(int* __restrict__ ptr, const int* __restrict__ bsum,
                        int n, int total) {
  int i = blockIdx.x * blockDim.x + threadIdx.x;
  if (i < n) ptr[i] += bsum[i >> 10];
  if (i == 0) ptr[n] = total;
}

// ---------------- Fused matmul + attention scores (users + items, one launch) ---------
// Writes fp32 feats (self path), fp16 feats + fp16 scores (gather path).
// May run IN PLACE (X == feat): each block reads only its own 64 rows into LDS
// before writing them back.
__global__ __launch_bounds__(256) void k_mm2(
    const float* Xu, const float* Xi,
    const float* __restrict__ Wu, const float* __restrict__ Wi,
    const float* __restrict__ a, int layer,
    float* featU, float* featI,
    __half* __restrict__ f16U, __half* __restrict__ f16I,
    __half* __restrict__ s16U, __half* __restrict__ s16I) {
  __shared__ float Wl[4096];
  __shared__ float Xs[4096];
  const bool isU = blockIdx.x < NB_U;
  const int N = isU ? U_N : I_N;
  const int base = (isU ? blockIdx.x : blockIdx.x - NB_U) * 64;
  const float* X = isU ? Xu : Xi;
  const float* W = isU ? Wu : Wi;
  float* feat = isU ? featU : featI;
  __half* f16 = isU ? f16U : f16I;
  __half* s16 = isU ? s16U : s16I;
  const int aoff = (layer == 1) ? (isU ? 0 : 8) : (isU ? 0 : 64);
  int t = threadIdx.x;

  if (layer == 1) {
#pragma unroll
    for (int k = 0; k < 4; k++) {
      int i = t + 256 * k;
      int h = i >> 7, d = (i >> 1) & 63, half = i & 1;
      float4 v = *(const float4*)(W + h * 512 + d * 8 + half * 4);
      *(float4*)(Wl + d * 64 + h * 8 + half * 4) = v;
    }
  } else {
#pragma unroll
    for (int k = 0; k < 4; k++) {
      int i = t + 256 * k;
      *(float4*)(Wl + i * 4) = *(const float4*)(W + i * 4);
    }
  }
#pragma unroll
  for (int k = 0; k < 4; k++) {
    int i = t + 256 * k;
    int r = i >> 4, ch = i & 15;
    int node = base + r;
    float4 v = make_float4(0.f, 0.f, 0.f, 0.f);
    if (node < N) v = *(const float4*)(X + (size_t)node * 64 + ch * 4);
    *(float4*)(Xs + r * 64 + ch * 4) = v;
  }
  __syncthreads();

  const int c0 = t & 31;
  const int rb = t >> 5;
  float acc0[8], acc1[8];
#pragma unroll
  for (int k = 0; k < 8; k++) { acc0[k] = 0.f; acc1[k] = 0.f; }

  for (int d0 = 0; d0 < 64; d0 += 4) {
    float2 wA = *(float2*)(Wl + (d0 + 0) * 64 + 2 * c0);
    float2 wB = *(float2*)(Wl + (d0 + 1) * 64 + 2 * c0);
    float2 wC = *(float2*)(Wl + (d0 + 2) * 64 + 2 * c0);
    float2 wD = *(float2*)(Wl + (d0 + 3) * 64 + 2 * c0);
#pragma unroll
    for (int k = 0; k < 8; k++) {
      float4 x = *(float4*)(Xs + (rb + 8 * k) * 64 + d0);
      acc0[k] += x.x * wA.x + x.y * wB.x + x.z * wC.x + x.w * wD.x;
      acc1[k] += x.x * wA.y + x.y * wB.y + x.z * wC.y + x.w * wD.y;
    }
  }

  float av0, av1;
  if (layer == 1) {
    int h = c0 >> 2, j = 2 * (c0 & 3);
    av0 = a[h * 16 + aoff + j];
    av1 = a[h * 16 + aoff + j + 1];
  } else {
    av0 = a[aoff + 2 * c0];
    av1 = a[aoff + 2 * c0 + 1];
  }
#pragma unroll
  for (int k = 0; k < 8; k++) {
    int node = base + rb + 8 * k;
    float s = acc0[k] * av0 + acc1[k] * av1;
    s += __shfl_xor(s, 1);
    s += __shfl_xor(s, 2);
    if (layer != 1) {
      s += __shfl_xor(s, 4);
      s += __shfl_xor(s, 8);
      s += __shfl_xor(s, 16);
    }
    if (node < N) {
      float2 f;
      f.x = acc0[k];
      f.y = acc1[k];
      *(float2*)(feat + (size_t)node * 64 + 2 * c0) = f;
      *(__half2*)(f16 + (size_t)node * 64 + 2 * c0) = __float22half2_rn(f);
      if (layer == 1) {
        if ((c0 & 3) == 0) s16[node * 8 + (c0 >> 2)] = __float2half_rn(s);
      } else {
        if (c0 == 0) s16[node] = __float2half_rn(s);
      }
    }
  }
}

// ---------------- Fused aggregation, IN PLACE (users + items, one launch) -------------
// One wave per node; 8 edges in flight (8 lanes/edge, 8 fp16 feats = 16B per lane).
// Gathers read ONLY the fp16 shadow tables; self path + output are fp32 in place.
__global__ void k_agg2(const int* __restrict__ ptr, const int* __restrict__ col,
                       float* selfU, float* selfI,
                       const __half* __restrict__ f16U, const __half* __restrict__ f16I,
                       const __half* __restrict__ s16U, const __half* __restrict__ s16I,
                       int layer) {
  int gid = blockIdx.x * blockDim.x + threadIdx.x;
  int n = gid >> 6;
  if (n >= UI_N) return;
  int l = threadIdx.x & 63;
  int g = l >> 3;       // edge group 0..7
  int cc = l & 7;       // feature chunk: halfs [cc*8, cc*8+8) == head cc in layer1
  bool isU = n < U_N;
  int nl = isU ? n : n - U_N;
  const __half* nbrF = isU ? f16I : f16U;
  const __half* nbrS = isU ? s16I : s16U;
  const __half* selfS = isU ? s16U : s16I;
  float* selfp = isU ? selfU : selfI;

  int sc, h;
  if (layer == 1) { sc = 8; h = cc; }
  else            { sc = 1; h = 0; }
  float sself = __half2float(selfS[(size_t)nl * sc + h]);

  int beg = ptr[n], end = ptr[n + 1];
  float acc[8];
#pragma unroll
  for (int k = 0; k < 8; k++) acc[k] = 0.f;
  float wsum = 0.f;
  for (int p = beg; p < end; p += 8) {
    int idx = p + g;
    bool valid = idx < end;
    int nb = col[valid ? idx : beg];
    float x = sself + __half2float(nbrS[(size_t)nb * sc + h]);
    float lx = (x >= 0.f) ? x : 0.2f * x;
    float w = valid ? __expf(-lx) : 0.f;
    wsum += w;
    float4 raw = *(const float4*)(nbrF + (size_t)nb * 64 + cc * 8);
    const __half2* hp = (const __half2*)&raw;
    float2 f0 = __half22float2(hp[0]);
    float2 f1 = __half22float2(hp[1]);
    float2 f2 = __half22float2(hp[2]);
    float2 f3 = __half22float2(hp[3]);
    acc[0] += w * f0.x; acc[1] += w * f0.y;
    acc[2] += w * f1.x; acc[3] += w * f1.y;
    acc[4] += w * f2.x; acc[5] += w * f2.y;
    acc[6] += w * f3.x; acc[7] += w * f3.y;
  }
#pragma unroll
  for (int k = 0; k < 8; k++) {
    acc[k] += __shfl_xor(acc[k], 8);
    acc[k] += __shfl_xor(acc[k], 16);
    acc[k] += __shfl_xor(acc[k], 32);
  }
  wsum += __shfl_xor(wsum, 8);
  wsum += __shfl_xor(wsum, 16);
  wsum += __shfl_xor(wsum, 32);

  if (l < 8) {
    float4 v0 = *(float4*)(selfp + (size_t)nl * 64 + cc * 8);
    float4 v1 = *(float4*)(selfp + (size_t)nl * 64 + cc * 8 + 4);
    if (end > beg) {
      float inv = 1.f / wsum;
      v0.x += acc[0] * inv; v0.y += acc[1] * inv;
      v0.z += acc[2] * inv; v0.w += acc[3] * inv;
      v1.x += acc[4] * inv; v1.y += acc[5] * inv;
      v1.z += acc[6] * inv; v1.w += acc[7] * inv;
    }
    v0.x = (v0.x > 0.f) ? v0.x : (__expf(v0.x) - 1.f);
    v0.y = (v0.y > 0.f) ? v0.y : (__expf(v0.y) - 1.f);
    v0.z = (v0.z > 0.f) ? v0.z : (__expf(v0.z) - 1.f);
    v0.w = (v0.w > 0.f) ? v0.w : (__expf(v0.w) - 1.f);
    v1.x = (v1.x > 0.f) ? v1.x : (__expf(v1.x) - 1.f);
    v1.y = (v1.y > 0.f) ? v1.y : (__expf(v1.y) - 1.f);
    v1.z = (v1.z > 0.f) ? v1.z : (__expf(v1.z) - 1.f);
    v1.w = (v1.w > 0.f) ? v1.w : (__expf(v1.w) - 1.f);
    *(float4*)(selfp + (size_t)nl * 64 + cc * 8) = v0;
    *(float4*)(selfp + (size_t)nl * 64 + cc * 8 + 4) = v1;
  }
}

// ---------------- Final pair dot ----------------
__global__ void k_dot(const int* __restrict__ uIdx, const int* __restrict__ iIdx,
                      const float* __restrict__ u_f, const float* __restrict__ i_f,
                      float* __restrict__ out) {
  int t = threadIdx.x;
  int pair = blockIdx.x * 16 + (t >> 4);
  int cc = t & 15;
  float4 a = *(const float4*)(u_f + (size_t)uIdx[pair] * 64 + cc * 4);
  float4 b = *(const float4*)(i_f + (size_t)iIdx[pair] * 64 + cc * 4);
  float v = a.x * b.x + a.y * b.y + a.z * b.z + a.w * b.w;
  v += __shfl_xor(v, 1);
  v += __shfl_xor(v, 2);
  v += __shfl_xor(v, 4);
  v += __shfl_xor(v, 8);
  if (cc == 0) out[pair] = v;
}

extern "C" void kernel_launch(void* const* d_in, const int* in_sizes, int n_in,
                              void* d_out, int out_size, void* d_ws, size_t ws_size,
                              hipStream_t stream) {
  const int* userIdx = (const int*)d_in[0];
  const int* itemIdx = (const int*)d_in[1];
  const int* edge_u = (const int*)d_in[2];
  const int* edge_i = (const int*)d_in[3];
  const float* uEmbd = (const float*)d_in[4];
  const float* iEmbd = (const float*)d_in[5];
  const float* Wu_h = (const float*)d_in[6];
  const float* Wi_h = (const float*)d_in[7];
  const float* a_h = (const float*)d_in[8];
  const float* Wu_out = (const float*)d_in[9];
  const float* Wi_out = (const float*)d_in[10];
  const float* a_out = (const float*)d_in[11];
  float* out = (float*)d_out;

  char* w = (char*)d_ws;
  size_t off = 0;
  auto alloc = [&](size_t bytes) -> void* {
    void* p = w + off;
    off += (bytes + 511) & ~(size_t)511;
    return p;
  };
  // counters block: cnt[UI_N] | cur[UI_N] | bcnt[NBK] — one contiguous memset
  int* cnt = (int*)alloc((size_t)(2 * UI_N + 1024) * 4);
  int* cur = cnt + UI_N;
  int* bcnt = cnt + 2 * UI_N;
  int* ptr = (int*)alloc((size_t)(UI_N + 1) * 4);
  int* bsum = (int*)alloc(1024);
  int* col = (int*)alloc((size_t)2 * E_N * 4);
  // union region: bucket storage (48 MB, dead after k_build2) aliases everything below
  size_t union_off = off;
  int2* storage = (int2*)alloc((size_t)NBK * CAP * 8);
  size_t end_storage = off;
  off = union_off;
  float* uF = (float*)alloc((size_t)U_N * 64 * 4);   // fp32 feats, all layers in place
  float* iF = (float*)alloc((size_t)I_N * 64 * 4);
  __half* f16U = (__half*)alloc((size_t)U_N * 64 * 2);
  __half* f16I = (__half*)alloc((size_t)I_N * 64 * 2);
  __half* s16U = (__half*)alloc((size_t)U_N * 8 * 2);
  __half* s16I = (__half*)alloc((size_t)I_N * 8 * 2);
  if (off < end_storage) off = end_storage;  // union extent

  // CSR/CSC build (shared by both layers)
  hipMemsetAsync(cnt, 0, (size_t)(2 * UI_N + 1024) * 4, stream);
  k_build1<<<256, 256, 0, stream>>>(edge_u, edge_i, cnt, bcnt, storage);
  const int nb1 = (UI_N + 1023) / 1024;  // 147
  k_scan1<<<nb1, 256, 0, stream>>>(cnt, ptr, bsum, UI_N);
  k_scan2<<<1, 256, 0, stream>>>(bsum, nb1);
  k_scan3<<<(UI_N + 255) / 256, 256, 0, stream>>>(ptr, bsum, UI_N, 2 * E_N);
  k_build2<<<NBK, 256, 0, stream>>>(bcnt, storage, ptr, cur, col);

  // Layer 1: mm writes fp32+fp16 feats & fp16 scores; agg runs in place on uF/iF
  k_mm2<<<NB_U + NB_I, 256, 0, stream>>>(uEmbd, iEmbd, Wu_h, Wi_h, a_h, 1,
                                         uF, iF, f16U, f16I, s16U, s16I);
  k_agg2<<<UI_N * 64 / 256, 256, 0, stream>>>(ptr, col, uF, iF, f16U, f16I,
                                              s16U, s16I, 1);

  // Layer 2: mm in place (X == feat), fp16 tables overwritten; agg in place
  k_mm2<<<NB_U + NB_I, 256, 0, stream>>>(uF, iF, Wu_out, Wi_out, a_out, 2,
                                         uF, iF, f16U, f16I, s16U, s16I);
  k_agg2<<<UI_N * 64 / 256, 256, 0, stream>>>(ptr, col, uF, iF, f16U, f16I,
                                              s16U, s16I, 2);

  // Final per-pair dot
  k_dot<<<B_N / 16, 256, 0, stream>>>(userIdx, itemIdx, uF, iF, out);
}

// Round 5
// 417.113 us; speedup vs baseline: 8.3409x; 1.3571x over previous
//
#include <hip/hip_runtime.h>
#include <hip/hip_fp16.h>

#define U_N 50000
#define I_N 100000
#define E_N 1600000
#define B_N 16384
#define UI_N (U_N + I_N)   // 150000
#define NB_U 782           // ceil(50000/64)
#define NB_I 1563          // ceil(100000/64)
#define NBK 586            // ceil(150000/256) buckets, 256 nodes each
#define CAP 10240          // entries per bucket (mean 8192 max, ~22 sigma margin)
#define NBLD 512           // blocks in k_build1
#define CHUNK (E_N / NBLD) // 3125 edges per block

// ---------------- CSR build: phase 1 (block-local binning, packed 4B entries) ---------
// entry = (key&255)<<17 | nbr   (nbr < 2^17; key bucket = key>>8)
__global__ __launch_bounds__(1024) void k_build1(
    const int* __restrict__ eu, const int* __restrict__ ei,
    int* __restrict__ bcnt, int* __restrict__ storage) {
  __shared__ int hist[NBK];
  __shared__ int lbase[NBK];
  __shared__ int loff[NBK];
  int t = threadIdx.x;
  for (int b = t; b < NBK; b += 1024) { hist[b] = 0; loff[b] = 0; }
  __syncthreads();
  int e0 = blockIdx.x * CHUNK;
  int e1 = e0 + CHUNK;
  for (int e = e0 + t; e < e1; e += 1024) {
    int u = eu[e];
    int k2 = U_N + ei[e];
    atomicAdd(&hist[u >> 8], 1);
    atomicAdd(&hist[k2 >> 8], 1);
  }
  __syncthreads();
  for (int b = t; b < NBK; b += 1024) {
    int h = hist[b];
    lbase[b] = h ? atomicAdd(&bcnt[b], h) : 0;
  }
  __syncthreads();
  for (int e = e0 + t; e < e1; e += 1024) {
    int u = eu[e], it = ei[e];
    int k2 = U_N + it;
    int b1 = u >> 8;
    int s1 = lbase[b1] + atomicAdd(&loff[b1], 1);
    storage[(size_t)b1 * CAP + s1] = ((u & 255) << 17) | it;
    int b2 = k2 >> 8;
    int s2 = lbase[b2] + atomicAdd(&loff[b2], 1);
    storage[(size_t)b2 * CAP + s2] = ((k2 & 255) << 17) | u;
  }
}

// ---------------- per-node degree counts from buckets (no global atomics) -------------
__global__ __launch_bounds__(256) void k_count(const int* __restrict__ bcnt,
                                               const int* __restrict__ storage,
                                               int* __restrict__ cnt) {
  __shared__ int c[256];
  int b = blockIdx.x;
  c[threadIdx.x] = 0;
  __syncthreads();
  int n = bcnt[b];
  const int* s = storage + (size_t)b * CAP;
  for (int i = threadIdx.x; i < n; i += 256) atomicAdd(&c[s[i] >> 17], 1);
  __syncthreads();
  int node = b * 256 + threadIdx.x;
  if (node < UI_N) cnt[node] = c[threadIdx.x];
}

// ---------------- CSR build: phase 2 (one block per bucket, LDS cursors) --------------
__global__ __launch_bounds__(256) void k_build2(const int* __restrict__ bcnt,
                                                const int* __restrict__ storage,
                                                const int* __restrict__ ptr,
                                                int* __restrict__ col) {
  __shared__ int pb[256];
  __shared__ int cur[256];
  int b = blockIdx.x;
  int node = b * 256 + threadIdx.x;
  pb[threadIdx.x] = (node < UI_N) ? ptr[node] : 0;
  cur[threadIdx.x] = 0;
  __syncthreads();
  int n = bcnt[b];
  const int* s = storage + (size_t)b * CAP;
  for (int i = threadIdx.x; i < n; i += 256) {
    int e = s[i];
    int local = e >> 17;
    int slot = pb[local] + atomicAdd(&cur[local], 1);
    col[slot] = e & 0x1FFFF;
  }
}

// ---------------- Prefix scans over per-node counts -> ptr ----------------
__global__ void k_scan1(const int* __restrict__ cnt, int* __restrict__ ptr,
                        int* __restrict__ bsum, int n) {
  __shared__ int lds[256];
  int t = threadIdx.x;
  int base = blockIdx.x * 1024 + t * 4;
  int v0 = (base + 0 < n) ? cnt[base + 0] : 0;
  int v1 = (base + 1 < n) ? cnt[base + 1] : 0;
  int v2 = (base + 2 < n) ? cnt[base + 2] : 0;
  int v3 = (base + 3 < n) ? cnt[base + 3] : 0;
  int s = v0 + v1 + v2 + v3;
  lds[t] = s;
  __syncthreads();
  int val = s;
  for (int off = 1; off < 256; off <<= 1) {
    int x = (t >= off) ? lds[t - off] : 0;
    __syncthreads();
    val += x;
    lds[t] = val;
    __syncthreads();
  }
  int excl = val - s;
  if (base + 0 < n) ptr[base + 0] = excl;
  if (base + 1 < n) ptr[base + 1] = excl + v0;
  if (base + 2 < n) ptr[base + 2] = excl + v0 + v1;
  if (base + 3 < n) ptr[base + 3] = excl + v0 + v1 + v2;
  if (t == 255) bsum[blockIdx.x] = val;
}

__global__ void k_scan2(int* __restrict__ bsum, int nb) {
  __shared__ int lds[256];
  int t = threadIdx.x;
  int v = (t < nb) ? bsum[t] : 0;
  lds[t] = v;
  __syncthreads();
  int val = v;
  for (int off = 1; off < 256; off <<= 1) {
    int x = (t >= off) ? lds[t - off] : 0;
    __syncthreads();
    val += x;
    lds[t] = val;
    __syncthreads();
  }
  if (t < nb) bsum[t] = val - v;
}

__global__ void k_scan3(int* __restrict__ ptr, const int* __restrict__ bsum,
                        int n, int total) {
  int i = blockIdx.x * blockDim.x + threadIdx.x;
  if (i < n) ptr[i] += bsum[i >> 10];
  if (i == 0) ptr[n] = total;
}

// ---------------- Fused matmul + attention scores (users + items, one launch) ---------
__global__ __launch_bounds__(256) void k_mm2(
    const float* Xu, const float* Xi,
    const float* __restrict__ Wu, const float* __restrict__ Wi,
    const float* __restrict__ a, int layer,
    float* featU, float* featI,
    __half* __restrict__ f16U, __half* __restrict__ f16I,
    __half* __restrict__ s16U, __half* __restrict__ s16I) {
  __shared__ float Wl[4096];
  __shared__ float Xs[4096];
  const bool isU = blockIdx.x < NB_U;
  const int N = isU ? U_N : I_N;
  const int base = (isU ? blockIdx.x : blockIdx.x - NB_U) * 64;
  const float* X = isU ? Xu : Xi;
  const float* W = isU ? Wu : Wi;
  float* feat = isU ? featU : featI;
  __half* f16 = isU ? f16U : f16I;
  __half* s16 = isU ? s16U : s16I;
  const int aoff = (layer == 1) ? (isU ? 0 : 8) : (isU ? 0 : 64);
  int t = threadIdx.x;

  if (layer == 1) {
#pragma unroll
    for (int k = 0; k < 4; k++) {
      int i = t + 256 * k;
      int h = i >> 7, d = (i >> 1) & 63, half = i & 1;
      float4 v = *(const float4*)(W + h * 512 + d * 8 + half * 4);
      *(float4*)(Wl + d * 64 + h * 8 + half * 4) = v;
    }
  } else {
#pragma unroll
    for (int k = 0; k < 4; k++) {
      int i = t + 256 * k;
      *(float4*)(Wl + i * 4) = *(const float4*)(W + i * 4);
    }
  }
#pragma unroll
  for (int k = 0; k < 4; k++) {
    int i = t + 256 * k;
    int r = i >> 4, ch = i & 15;
    int node = base + r;
    float4 v = make_float4(0.f, 0.f, 0.f, 0.f);
    if (node < N) v = *(const float4*)(X + (size_t)node * 64 + ch * 4);
    *(float4*)(Xs + r * 64 + ch * 4) = v;
  }
  __syncthreads();

  const int c0 = t & 31;
  const int rb = t >> 5;
  float acc0[8], acc1[8];
#pragma unroll
  for (int k = 0; k < 8; k++) { acc0[k] = 0.f; acc1[k] = 0.f; }

  for (int d0 = 0; d0 < 64; d0 += 4) {
    float2 wA = *(float2*)(Wl + (d0 + 0) * 64 + 2 * c0);
    float2 wB = *(float2*)(Wl + (d0 + 1) * 64 + 2 * c0);
    float2 wC = *(float2*)(Wl + (d0 + 2) * 64 + 2 * c0);
    float2 wD = *(float2*)(Wl + (d0 + 3) * 64 + 2 * c0);
#pragma unroll
    for (int k = 0; k < 8; k++) {
      float4 x = *(float4*)(Xs + (rb + 8 * k) * 64 + d0);
      acc0[k] += x.x * wA.x + x.y * wB.x + x.z * wC.x + x.w * wD.x;
      acc1[k] += x.x * wA.y + x.y * wB.y + x.z * wC.y + x.w * wD.y;
    }
  }

  float av0, av1;
  if (layer == 1) {
    int h = c0 >> 2, j = 2 * (c0 & 3);
    av0 = a[h * 16 + aoff + j];
    av1 = a[h * 16 + aoff + j + 1];
  } else {
    av0 = a[aoff + 2 * c0];
    av1 = a[aoff + 2 * c0 + 1];
  }
#pragma unroll
  for (int k = 0; k < 8; k++) {
    int node = base + rb + 8 * k;
    float s = acc0[k] * av0 + acc1[k] * av1;
    s += __shfl_xor(s, 1);
    s += __shfl_xor(s, 2);
    if (layer != 1) {
      s += __shfl_xor(s, 4);
      s += __shfl_xor(s, 8);
      s += __shfl_xor(s, 16);
    }
    if (node < N) {
      float2 f;
      f.x = acc0[k];
      f.y = acc1[k];
      *(float2*)(feat + (size_t)node * 64 + 2 * c0) = f;
      *(__half2*)(f16 + (size_t)node * 64 + 2 * c0) = __float22half2_rn(f);
      if (layer == 1) {
        if ((c0 & 3) == 0) s16[node * 8 + (c0 >> 2)] = __float2half_rn(s);
      } else {
        if (c0 == 0) s16[node] = __float2half_rn(s);
      }
    }
  }
}

// ---------------- Fused aggregation, IN PLACE (users + items, one launch) -------------
__global__ void k_agg2(const int* __restrict__ ptr, const int* __restrict__ col,
                       float* selfU, float* selfI,
                       const __half* __restrict__ f16U, const __half* __restrict__ f16I,
                       const __half* __restrict__ s16U, const __half* __restrict__ s16I,
                       int layer) {
  int gid = blockIdx.x * blockDim.x + threadIdx.x;
  int n = gid >> 6;
  if (n >= UI_N) return;
  int l = threadIdx.x & 63;
  int g = l >> 3;       // edge group 0..7
  int cc = l & 7;       // feature chunk: halfs [cc*8, cc*8+8) == head cc in layer1
  bool isU = n < U_N;
  int nl = isU ? n : n - U_N;
  const __half* nbrF = isU ? f16I : f16U;
  const __half* nbrS = isU ? s16I : s16U;
  const __half* selfS = isU ? s16U : s16I;
  float* selfp = isU ? selfU : selfI;

  int sc, h;
  if (layer == 1) { sc = 8; h = cc; }
  else            { sc = 1; h = 0; }
  float sself = __half2float(selfS[(size_t)nl * sc + h]);

  int beg = ptr[n], end = ptr[n + 1];
  float acc[8];
#pragma unroll
  for (int k = 0; k < 8; k++) acc[k] = 0.f;
  float wsum = 0.f;
  for (int p = beg; p < end; p += 8) {
    int idx = p + g;
    bool valid = idx < end;
    int nb = col[valid ? idx : beg];
    float x = sself + __half2float(nbrS[(size_t)nb * sc + h]);
    float lx = (x >= 0.f) ? x : 0.2f * x;
    float w = valid ? __expf(-lx) : 0.f;
    wsum += w;
    float4 raw = *(const float4*)(nbrF + (size_t)nb * 64 + cc * 8);
    const __half2* hp = (const __half2*)&raw;
    float2 f0 = __half22float2(hp[0]);
    float2 f1 = __half22float2(hp[1]);
    float2 f2 = __half22float2(hp[2]);
    float2 f3 = __half22float2(hp[3]);
    acc[0] += w * f0.x; acc[1] += w * f0.y;
    acc[2] += w * f1.x; acc[3] += w * f1.y;
    acc[4] += w * f2.x; acc[5] += w * f2.y;
    acc[6] += w * f3.x; acc[7] += w * f3.y;
  }
#pragma unroll
  for (int k = 0; k < 8; k++) {
    acc[k] += __shfl_xor(acc[k], 8);
    acc[k] += __shfl_xor(acc[k], 16);
    acc[k] += __shfl_xor(acc[k], 32);
  }
  wsum += __shfl_xor(wsum, 8);
  wsum += __shfl_xor(wsum, 16);
  wsum += __shfl_xor(wsum, 32);

  if (l < 8) {
    float4 v0 = *(float4*)(selfp + (size_t)nl * 64 + cc * 8);
    float4 v1 = *(float4*)(selfp + (size_t)nl * 64 + cc * 8 + 4);
    if (end > beg) {
      float inv = 1.f / wsum;
      v0.x += acc[0] * inv; v0.y += acc[1] * inv;
      v0.z += acc[2] * inv; v0.w += acc[3] * inv;
      v1.x += acc[4] * inv; v1.y += acc[5] * inv;
      v1.z += acc[6] * inv; v1.w += acc[7] * inv;
    }
    v0.x = (v0.x > 0.f) ? v0.x : (__expf(v0.x) - 1.f);
    v0.y = (v0.y > 0.f) ? v0.y : (__expf(v0.y) - 1.f);
    v0.z = (v0.z > 0.f) ? v0.z : (__expf(v0.z) - 1.f);
    v0.w = (v0.w > 0.f) ? v0.w : (__expf(v0.w) - 1.f);
    v1.x = (v1.x > 0.f) ? v1.x : (__expf(v1.x) - 1.f);
    v1.y = (v1.y > 0.f) ? v1.y : (__expf(v1.y) - 1.f);
    v1.z = (v1.z > 0.f) ? v1.z : (__expf(v1.z) - 1.f);
    v1.w = (v1.w > 0.f) ? v1.w : (__expf(v1.w) - 1.f);
    *(float4*)(selfp + (size_t)nl * 64 + cc * 8) = v0;
    *(float4*)(selfp + (size_t)nl * 64 + cc * 8 + 4) = v1;
  }
}

// ---------------- Final pair dot ----------------
__global__ void k_dot(const int* __restrict__ uIdx, const int* __restrict__ iIdx,
                      const float* __restrict__ u_f, const float* __restrict__ i_f,
                      float* __restrict__ out) {
  int t = threadIdx.x;
  int pair = blockIdx.x * 16 + (t >> 4);
  int cc = t & 15;
  float4 a = *(const float4*)(u_f + (size_t)uIdx[pair] * 64 + cc * 4);
  float4 b = *(const float4*)(i_f + (size_t)iIdx[pair] * 64 + cc * 4);
  float v = a.x * b.x + a.y * b.y + a.z * b.z + a.w * b.w;
  v += __shfl_xor(v, 1);
  v += __shfl_xor(v, 2);
  v += __shfl_xor(v, 4);
  v += __shfl_xor(v, 8);
  if (cc == 0) out[pair] = v;
}

extern "C" void kernel_launch(void* const* d_in, const int* in_sizes, int n_in,
                              void* d_out, int out_size, void* d_ws, size_t ws_size,
                              hipStream_t stream) {
  const int* userIdx = (const int*)d_in[0];
  const int* itemIdx = (const int*)d_in[1];
  const int* edge_u = (const int*)d_in[2];
  const int* edge_i = (const int*)d_in[3];
  const float* uEmbd = (const float*)d_in[4];
  const float* iEmbd = (const float*)d_in[5];
  const float* Wu_h = (const float*)d_in[6];
  const float* Wi_h = (const float*)d_in[7];
  const float* a_h = (const float*)d_in[8];
  const float* Wu_out = (const float*)d_in[9];
  const float* Wi_out = (const float*)d_in[10];
  const float* a_out = (const float*)d_in[11];
  float* out = (float*)d_out;

  char* w = (char*)d_ws;
  size_t off = 0;
  auto alloc = [&](size_t bytes) -> void* {
    void* p = w + off;
    off += (bytes + 511) & ~(size_t)511;
    return p;
  };
  int* bcnt = (int*)alloc((size_t)NBK * 4);         // memset (only counter needing init)
  int* cnt = (int*)alloc((size_t)UI_N * 4);         // fully written by k_count
  int* ptr = (int*)alloc((size_t)(UI_N + 1) * 4);
  int* bsum = (int*)alloc(1024);
  int* col = (int*)alloc((size_t)2 * E_N * 4);
  // union region: bucket storage (24 MB, dead after k_build2) aliases everything below
  size_t union_off = off;
  int* storage = (int*)alloc((size_t)NBK * CAP * 4);
  size_t end_storage = off;
  off = union_off;
  float* uF = (float*)alloc((size_t)U_N * 64 * 4);   // fp32 feats, all layers in place
  float* iF = (float*)alloc((size_t)I_N * 64 * 4);
  __half* f16U = (__half*)alloc((size_t)U_N * 64 * 2);
  __half* f16I = (__half*)alloc((size_t)I_N * 64 * 2);
  __half* s16U = (__half*)alloc((size_t)U_N * 8 * 2);
  __half* s16I = (__half*)alloc((size_t)I_N * 8 * 2);
  if (off < end_storage) off = end_storage;  // union extent

  // CSR/CSC build (shared by both layers)
  hipMemsetAsync(bcnt, 0, (size_t)NBK * 4, stream);
  k_build1<<<NBLD, 1024, 0, stream>>>(edge_u, edge_i, bcnt, storage);
  k_count<<<NBK, 256, 0, stream>>>(bcnt, storage, cnt);
  const int nb1 = (UI_N + 1023) / 1024;  // 147
  k_scan1<<<nb1, 256, 0, stream>>>(cnt, ptr, bsum, UI_N);
  k_scan2<<<1, 256, 0, stream>>>(bsum, nb1);
  k_scan3<<<(UI_N + 255) / 256, 256, 0, stream>>>(ptr, bsum, UI_N, 2 * E_N);
  k_build2<<<NBK, 256, 0, stream>>>(bcnt, storage, ptr, col);

  // Layer 1: mm writes fp32+fp16 feats & fp16 scores; agg runs in place on uF/iF
  k_mm2<<<NB_U + NB_I, 256, 0, stream>>>(uEmbd, iEmbd, Wu_h, Wi_h, a_h, 1,
                                         uF, iF, f16U, f16I, s16U, s16I);
  k_agg2<<<UI_N * 64 / 256, 256, 0, stream>>>(ptr, col, uF, iF, f16U, f16I,
                                              s16U, s16I, 1);

  // Layer 2: mm in place (X == feat), fp16 tables overwritten; agg in place
  k_mm2<<<NB_U + NB_I, 256, 0, stream>>>(uF, iF, Wu_out, Wi_out, a_out, 2,
                                         uF, iF, f16U, f16I, s16U, s16I);
  k_agg2<<<UI_N * 64 / 256, 256, 0, stream>>>(ptr, col, uF, iF, f16U, f16I,
                                              s16U, s16I, 2);

  // Final per-pair dot
  k_dot<<<B_N / 16, 256, 0, stream>>>(userIdx, itemIdx, uF, iF, out);
}